// Round 3
// baseline (14170.352 us; speedup 1.0000x reference)
//
#include <hip/hip_runtime.h>

#define S_ 512
#define B_ 64
#define I_ 1024
#define H_ 1024
#define G_ 4096  // 4*H

typedef _Float16 f16x4 __attribute__((ext_vector_type(4)));
typedef _Float16 f16x8 __attribute__((ext_vector_type(8)));
typedef float f32x4 __attribute__((ext_vector_type(4)));

// ---------------- f32 -> f16 (plain) ----------------
__global__ __launch_bounds__(256) void cvt_f32_f16(const float* __restrict__ src,
                                                   _Float16* __restrict__ dst, int n) {
  const int stride = gridDim.x * blockDim.x * 4;
  for (long i = (long)(blockIdx.x * blockDim.x + threadIdx.x) * 4; i < n; i += stride) {
    const float4 v = *(const float4*)(src + i);
    f16x4 o;
    o.x = (_Float16)v.x;
    o.y = (_Float16)v.y;
    o.z = (_Float16)v.z;
    o.w = (_Float16)v.w;
    *(f16x4*)(dst + i) = o;
  }
}

// ---------------- f32 -> (f16 hi, f16 lo) split ----------------
__global__ __launch_bounds__(256) void cvt_split(const float* __restrict__ src,
                                                 _Float16* __restrict__ hi,
                                                 _Float16* __restrict__ lo, int n) {
  const int stride = gridDim.x * blockDim.x * 4;
  for (long i = (long)(blockIdx.x * blockDim.x + threadIdx.x) * 4; i < n; i += stride) {
    const float4 v = *(const float4*)(src + i);
    f16x4 h, l;
    h.x = (_Float16)v.x; l.x = (_Float16)(v.x - (float)h.x);
    h.y = (_Float16)v.y; l.y = (_Float16)(v.y - (float)h.y);
    h.z = (_Float16)v.z; l.z = (_Float16)(v.z - (float)h.z);
    h.w = (_Float16)v.w; l.w = (_Float16)(v.w - (float)h.w);
    *(f16x4*)(hi + i) = h;
    *(f16x4*)(lo + i) = l;
  }
}

// ---------------- async global->LDS helper (16B per lane) ----------------
__device__ __forceinline__ void gload16(const void* g, void* l) {
  __builtin_amdgcn_global_load_lds(
      (const __attribute__((address_space(1))) unsigned int*)g,
      (__attribute__((address_space(3))) unsigned int*)l, 16, 0, 0);
}

// ---------------- x_gates GEMM (unchanged from R2, verified) ----------------
template <typename XGT>
__global__ __launch_bounds__(256) void gemm_xg(const float* __restrict__ A,
                                               const _Float16* __restrict__ Bhi,
                                               const _Float16* __restrict__ Blo,
                                               const float* __restrict__ bx,
                                               const float* __restrict__ bh,
                                               XGT* __restrict__ C) {
  __shared__ __align__(16) float As[128 * 32];
  __shared__ __align__(16) _Float16 BsH[128 * 32];
  __shared__ __align__(16) _Float16 BsL[128 * 32];
  const int tileN = (blockIdx.x & 31) << 7;
  const int tileM = (blockIdx.x >> 5) << 7;
  const int w = threadIdx.x >> 6;
  const int lane = threadIdx.x & 63;
  const int wm = w & 1, wn = w >> 1;

  const int arow = lane >> 3;
  const int acol = (lane & 7) << 2;
  const float* ap0 = A + (long)(tileM + (4 * w + 0) * 8 + arow) * I_ + acol;
  const float* ap1 = A + (long)(tileM + (4 * w + 1) * 8 + arow) * I_ + acol;
  const float* ap2 = A + (long)(tileM + (4 * w + 2) * 8 + arow) * I_ + acol;
  const float* ap3 = A + (long)(tileM + (4 * w + 3) * 8 + arow) * I_ + acol;
  const int brow = lane >> 2;
  const int bcol = (lane & 3) << 3;
  const _Float16* bh0 = Bhi + (long)(tileN + (2 * w + 0) * 16 + brow) * I_ + bcol;
  const _Float16* bh1 = Bhi + (long)(tileN + (2 * w + 1) * 16 + brow) * I_ + bcol;
  const _Float16* bl0 = Blo + (long)(tileN + (2 * w + 0) * 16 + brow) * I_ + bcol;
  const _Float16* bl1 = Blo + (long)(tileN + (2 * w + 1) * 16 + brow) * I_ + bcol;

  f32x4 acc[4][4] = {};
  const int fr = lane & 15;
  const int fk = (lane >> 4) << 3;

  for (int kk = 0; kk < I_; kk += 32) {
    gload16(ap0 + kk, &As[(4 * w + 0) * 256]);
    gload16(ap1 + kk, &As[(4 * w + 1) * 256]);
    gload16(ap2 + kk, &As[(4 * w + 2) * 256]);
    gload16(ap3 + kk, &As[(4 * w + 3) * 256]);
    gload16(bh0 + kk, &BsH[(2 * w + 0) * 512]);
    gload16(bh1 + kk, &BsH[(2 * w + 1) * 512]);
    gload16(bl0 + kk, &BsL[(2 * w + 0) * 512]);
    gload16(bl1 + kk, &BsL[(2 * w + 1) * 512]);
    __syncthreads();
    f16x8 ah[4], al[4], bhf[4], blf[4];
#pragma unroll
    for (int i = 0; i < 4; ++i) {
      const float* ap = &As[(wm * 64 + i * 16 + fr) * 32 + fk];
      const float4 v0 = *(const float4*)ap;
      const float4 v1 = *(const float4*)(ap + 4);
      float vv[8] = {v0.x, v0.y, v0.z, v0.w, v1.x, v1.y, v1.z, v1.w};
#pragma unroll
      for (int j = 0; j < 8; ++j) {
        const _Float16 hi = (_Float16)vv[j];
        ah[i][j] = hi;
        al[i][j] = (_Float16)(vv[j] - (float)hi);
      }
      bhf[i] = *(const f16x8*)&BsH[(wn * 64 + i * 16 + fr) * 32 + fk];
      blf[i] = *(const f16x8*)&BsL[(wn * 64 + i * 16 + fr) * 32 + fk];
    }
#pragma unroll
    for (int i = 0; i < 4; ++i)
#pragma unroll
      for (int j = 0; j < 4; ++j) {
        acc[i][j] = __builtin_amdgcn_mfma_f32_16x16x32_f16(ah[i], bhf[j], acc[i][j], 0, 0, 0);
        acc[i][j] = __builtin_amdgcn_mfma_f32_16x16x32_f16(al[i], bhf[j], acc[i][j], 0, 0, 0);
        acc[i][j] = __builtin_amdgcn_mfma_f32_16x16x32_f16(ah[i], blf[j], acc[i][j], 0, 0, 0);
      }
    __syncthreads();
  }

#pragma unroll
  for (int j = 0; j < 4; ++j) {
    const int col = tileN + wn * 64 + j * 16 + fr;
    const float bias = bx[col] + bh[col];
#pragma unroll
    for (int i = 0; i < 4; ++i) {
      const int row0 = tileM + wm * 64 + i * 16 + ((lane >> 4) << 2);
#pragma unroll
      for (int r = 0; r < 4; ++r)
        C[(long)(row0 + r) * G_ + col] = (XGT)(acc[i][j][r] + bias);
    }
  }
}

// ---------------- barrier counter reset (every launch, stream-ordered) ----------------
__global__ void zero_counters(unsigned int* c) { c[threadIdx.x] = 0; }

// ---------------- persistent LSTM scan ----------------
// 256 WGs x 256 threads, 1/CU. WG = (bg, hs). Wave w = gate. Wh in 128 VGPRs/lane.
// 4 independent barrier groups (one per bg): only WGs sharing batches must sync.
template <typename XGT>
__global__ __launch_bounds__(256, 1) void lstm_scan(
    const XGT* __restrict__ xg, const _Float16* __restrict__ Whh,
    _Float16* __restrict__ hhi0, _Float16* __restrict__ hhi1,
    _Float16* __restrict__ hlo0, _Float16* __restrict__ hlo1,
    float* __restrict__ out, float* __restrict__ hT, float* __restrict__ cT,
    unsigned int* __restrict__ barcnt) {
  __shared__ float gbuf[4][16][16];
  const int bg = blockIdx.x >> 6;
  const int hs = blockIdx.x & 63;
  const int w = threadIdx.x >> 6;
  const int lane = threadIdx.x & 63;
  const int fr = lane & 15;
  const int fk = (lane >> 4) << 3;

  // ---- Wh -> registers: lane's B-fragments for all K. 32 x f16x8 = 128 VGPR ----
  f16x8 wreg[32];
  {
    const _Float16* wrow = Whh + (long)(w * H_ + hs * 16 + fr) * H_ + fk;
#pragma unroll
    for (int it = 0; it < 16; ++it) {
      wreg[2 * it] = *(const f16x8*)(wrow + it * 64);
      wreg[2 * it + 1] = *(const f16x8*)(wrow + it * 64 + 32);
    }
  }

  const int tid = threadIdx.x;
  const int b = tid >> 4, j = tid & 15;
  const int gb = bg * 16 + b;
  const int gj = hs * 16 + j;
  float c = 0.f;
  unsigned int* cnt = barcnt + bg * 64;  // 256B-separated counters

  // xg prefetch for t=0
  float gi = (float)xg[(long)gb * G_ + gj];
  float gf = (float)xg[(long)gb * G_ + gj + H_];
  float gg = (float)xg[(long)gb * G_ + gj + 2 * H_];
  float go = (float)xg[(long)gb * G_ + gj + 3 * H_];

  const long hoff = (long)(bg * 16 + fr) * H_ + fk;

  for (int t = 0; t < S_; ++t) {
    if (t > 0) {
      // read h written at t-1: buffer (t-1)&1 -> t odd reads buf0, t even reads buf1
      const _Float16* hh = ((t & 1) ? hhi0 : hhi1) + hoff;
      const _Float16* hl = ((t & 1) ? hlo0 : hlo1) + hoff;
      f32x4 acc0 = {}, acc1 = {};
#pragma unroll
      for (int it = 0; it < 16; ++it) {
        const int kk = it * 64;
        acc0 = __builtin_amdgcn_mfma_f32_16x16x32_f16(*(const f16x8*)(hh + kk), wreg[2 * it], acc0, 0, 0, 0);
        acc0 = __builtin_amdgcn_mfma_f32_16x16x32_f16(*(const f16x8*)(hl + kk), wreg[2 * it], acc0, 0, 0, 0);
        acc1 = __builtin_amdgcn_mfma_f32_16x16x32_f16(*(const f16x8*)(hh + kk + 32), wreg[2 * it + 1], acc1, 0, 0, 0);
        acc1 = __builtin_amdgcn_mfma_f32_16x16x32_f16(*(const f16x8*)(hl + kk + 32), wreg[2 * it + 1], acc1, 0, 0, 0);
      }
#pragma unroll
      for (int r = 0; r < 4; ++r)
        gbuf[w][((lane >> 4) << 2) + r][fr] = acc0[r] + acc1[r];
      __syncthreads();
      gi += gbuf[0][b][j];
      gf += gbuf[1][b][j];
      gg += gbuf[2][b][j];
      go += gbuf[3][b][j];
    }

    const float iv = 1.f / (1.f + __expf(-gi));
    const float fv = 1.f / (1.f + __expf(-gf));
    const float gv = tanhf(gg);
    const float ov = 1.f / (1.f + __expf(-go));
    c = fv * c + iv * gv;
    const float hn = ov * tanhf(c);

    // write h for step t+1 into buffer t&1
    _Float16* whi = ((t & 1) ? hhi1 : hhi0);
    _Float16* wlo = ((t & 1) ? hlo1 : hlo0);
    const _Float16 hh16 = (_Float16)hn;
    whi[gb * H_ + gj] = hh16;
    wlo[gb * H_ + gj] = (_Float16)(hn - (float)hh16);
    out[((long)gb * S_ + t) * H_ + gj] = hn;

    if (t + 1 < S_) {
      // prefetch next xg before the barrier (latency hides in barrier wait)
      const XGT* xq = xg + ((long)(t + 1) * B_ + gb) * G_ + gj;
      gi = (float)xq[0];
      gf = (float)xq[H_];
      gg = (float)xq[2 * H_];
      go = (float)xq[3 * H_];
      // group barrier: 64 WGs sharing this bg
      __syncthreads();  // drains vmcnt -> all WG stores in (local) L2
      if (tid == 0) {
        __hip_atomic_fetch_add(cnt, 1u, __ATOMIC_RELEASE, __HIP_MEMORY_SCOPE_AGENT);
        const unsigned int target = 64u * (unsigned)(t + 1);
        while (__hip_atomic_load(cnt, __ATOMIC_RELAXED, __HIP_MEMORY_SCOPE_AGENT) < target)
          __builtin_amdgcn_s_sleep(2);
      }
      __syncthreads();
      // per-thread acquire: orders the next iteration's h loads after the barrier
      (void)__hip_atomic_load(cnt, __ATOMIC_ACQUIRE, __HIP_MEMORY_SCOPE_AGENT);
    } else {
      hT[gb * H_ + gj] = hn;
      cT[gb * H_ + gj] = c;
    }
  }
}

// ---------------- launch ----------------
extern "C" void kernel_launch(void* const* d_in, const int* in_sizes, int n_in,
                              void* d_out, int out_size, void* d_ws, size_t ws_size,
                              hipStream_t stream) {
  const float* x = (const float*)d_in[0];
  const float* Wx = (const float*)d_in[1];
  const float* bx = (const float*)d_in[2];
  const float* Wh = (const float*)d_in[3];
  const float* bh = (const float*)d_in[4];

  float* out = (float*)d_out;            // [64][512][1024]
  float* hT = out + (long)B_ * S_ * H_;  // [64][1024]
  float* cT = hT + (long)B_ * H_;        // [64][1024]

  char* ws = (char*)d_ws;
  _Float16* Wxhi = (_Float16*)ws;                     // 8 MB
  _Float16* Wxlo = (_Float16*)(ws + (8l << 20));      // 8 MB
  _Float16* Whh = (_Float16*)(ws + (16l << 20));      // 8 MB
  char* st = ws + (24l << 20);
  _Float16* hhi0 = (_Float16*)(st);                   // 128 KB
  _Float16* hhi1 = (_Float16*)(st + (128l << 10));    // 128 KB
  _Float16* hlo0 = (_Float16*)(st + (256l << 10));    // 128 KB
  _Float16* hlo1 = (_Float16*)(st + (384l << 10));    // 128 KB
  unsigned int* barcnt = (unsigned int*)(st + (512l << 10));  // 1 KB
  char* xg_raw = ws + (32l << 20);

  cvt_split<<<256, 256, 0, stream>>>(Wx, Wxhi, Wxlo, G_ * I_);
  cvt_f32_f16<<<256, 256, 0, stream>>>(Wh, Whh, G_ * H_);
  zero_counters<<<1, 256, 0, stream>>>(barcnt);

  const size_t needA = (32ll << 20) + (long long)S_ * B_ * G_ * 4;  // f32 x_gates
  const int nGemmBlk = (S_ * B_ / 128) * (G_ / 128);

  if (ws_size >= needA) {
    float* xg = (float*)xg_raw;
    gemm_xg<float><<<nGemmBlk, 256, 0, stream>>>(x, Wxhi, Wxlo, bx, bh, xg);
    lstm_scan<float><<<256, 256, 0, stream>>>(xg, Whh, hhi0, hhi1, hlo0, hlo1, out, hT, cT, barcnt);
  } else {
    _Float16* xg = (_Float16*)xg_raw;
    gemm_xg<_Float16><<<nGemmBlk, 256, 0, stream>>>(x, Wxhi, Wxlo, bx, bh, xg);
    lstm_scan<_Float16><<<256, 256, 0, stream>>>(xg, Whh, hhi0, hhi1, hlo0, hlo1, out, hT, cT, barcnt);
  }
}

// Round 4
// 12476.123 us; speedup vs baseline: 1.1358x; 1.1358x over previous
//
#include <hip/hip_runtime.h>

#define S_ 512
#define B_ 64
#define I_ 1024
#define H_ 1024
#define G_ 4096  // 4*H

typedef _Float16 f16x4 __attribute__((ext_vector_type(4)));
typedef _Float16 f16x8 __attribute__((ext_vector_type(8)));
typedef float f32x4 __attribute__((ext_vector_type(4)));

// ---------------- f32 -> f16 (plain) ----------------
__global__ __launch_bounds__(256) void cvt_f32_f16(const float* __restrict__ src,
                                                   _Float16* __restrict__ dst, int n) {
  const int stride = gridDim.x * blockDim.x * 4;
  for (long i = (long)(blockIdx.x * blockDim.x + threadIdx.x) * 4; i < n; i += stride) {
    const float4 v = *(const float4*)(src + i);
    f16x4 o;
    o.x = (_Float16)v.x;
    o.y = (_Float16)v.y;
    o.z = (_Float16)v.z;
    o.w = (_Float16)v.w;
    *(f16x4*)(dst + i) = o;
  }
}

// ---------------- f32 -> (f16 hi, f16 lo) split ----------------
__global__ __launch_bounds__(256) void cvt_split(const float* __restrict__ src,
                                                 _Float16* __restrict__ hi,
                                                 _Float16* __restrict__ lo, int n) {
  const int stride = gridDim.x * blockDim.x * 4;
  for (long i = (long)(blockIdx.x * blockDim.x + threadIdx.x) * 4; i < n; i += stride) {
    const float4 v = *(const float4*)(src + i);
    f16x4 h, l;
    h.x = (_Float16)v.x; l.x = (_Float16)(v.x - (float)h.x);
    h.y = (_Float16)v.y; l.y = (_Float16)(v.y - (float)h.y);
    h.z = (_Float16)v.z; l.z = (_Float16)(v.z - (float)h.z);
    h.w = (_Float16)v.w; l.w = (_Float16)(v.w - (float)h.w);
    *(f16x4*)(hi + i) = h;
    *(f16x4*)(lo + i) = l;
  }
}

// ---------------- async global->LDS helper (16B per lane) ----------------
__device__ __forceinline__ void gload16(const void* g, void* l) {
  __builtin_amdgcn_global_load_lds(
      (const __attribute__((address_space(1))) unsigned int*)g,
      (__attribute__((address_space(3))) unsigned int*)l, 16, 0, 0);
}

// ---------------- x_gates GEMM (unchanged, verified R2/R3) ----------------
template <typename XGT>
__global__ __launch_bounds__(256) void gemm_xg(const float* __restrict__ A,
                                               const _Float16* __restrict__ Bhi,
                                               const _Float16* __restrict__ Blo,
                                               const float* __restrict__ bx,
                                               const float* __restrict__ bh,
                                               XGT* __restrict__ C) {
  __shared__ __align__(16) float As[128 * 32];
  __shared__ __align__(16) _Float16 BsH[128 * 32];
  __shared__ __align__(16) _Float16 BsL[128 * 32];
  const int tileN = (blockIdx.x & 31) << 7;
  const int tileM = (blockIdx.x >> 5) << 7;
  const int w = threadIdx.x >> 6;
  const int lane = threadIdx.x & 63;
  const int wm = w & 1, wn = w >> 1;

  const int arow = lane >> 3;
  const int acol = (lane & 7) << 2;
  const float* ap0 = A + (long)(tileM + (4 * w + 0) * 8 + arow) * I_ + acol;
  const float* ap1 = A + (long)(tileM + (4 * w + 1) * 8 + arow) * I_ + acol;
  const float* ap2 = A + (long)(tileM + (4 * w + 2) * 8 + arow) * I_ + acol;
  const float* ap3 = A + (long)(tileM + (4 * w + 3) * 8 + arow) * I_ + acol;
  const int brow = lane >> 2;
  const int bcol = (lane & 3) << 3;
  const _Float16* bh0 = Bhi + (long)(tileN + (2 * w + 0) * 16 + brow) * I_ + bcol;
  const _Float16* bh1 = Bhi + (long)(tileN + (2 * w + 1) * 16 + brow) * I_ + bcol;
  const _Float16* bl0 = Blo + (long)(tileN + (2 * w + 0) * 16 + brow) * I_ + bcol;
  const _Float16* bl1 = Blo + (long)(tileN + (2 * w + 1) * 16 + brow) * I_ + bcol;

  f32x4 acc[4][4] = {};
  const int fr = lane & 15;
  const int fk = (lane >> 4) << 3;

  for (int kk = 0; kk < I_; kk += 32) {
    gload16(ap0 + kk, &As[(4 * w + 0) * 256]);
    gload16(ap1 + kk, &As[(4 * w + 1) * 256]);
    gload16(ap2 + kk, &As[(4 * w + 2) * 256]);
    gload16(ap3 + kk, &As[(4 * w + 3) * 256]);
    gload16(bh0 + kk, &BsH[(2 * w + 0) * 512]);
    gload16(bh1 + kk, &BsH[(2 * w + 1) * 512]);
    gload16(bl0 + kk, &BsL[(2 * w + 0) * 512]);
    gload16(bl1 + kk, &BsL[(2 * w + 1) * 512]);
    __syncthreads();
    f16x8 ah[4], al[4], bhf[4], blf[4];
#pragma unroll
    for (int i = 0; i < 4; ++i) {
      const float* ap = &As[(wm * 64 + i * 16 + fr) * 32 + fk];
      const float4 v0 = *(const float4*)ap;
      const float4 v1 = *(const float4*)(ap + 4);
      float vv[8] = {v0.x, v0.y, v0.z, v0.w, v1.x, v1.y, v1.z, v1.w};
#pragma unroll
      for (int j = 0; j < 8; ++j) {
        const _Float16 hi = (_Float16)vv[j];
        ah[i][j] = hi;
        al[i][j] = (_Float16)(vv[j] - (float)hi);
      }
      bhf[i] = *(const f16x8*)&BsH[(wn * 64 + i * 16 + fr) * 32 + fk];
      blf[i] = *(const f16x8*)&BsL[(wn * 64 + i * 16 + fr) * 32 + fk];
    }
#pragma unroll
    for (int i = 0; i < 4; ++i)
#pragma unroll
      for (int j = 0; j < 4; ++j) {
        acc[i][j] = __builtin_amdgcn_mfma_f32_16x16x32_f16(ah[i], bhf[j], acc[i][j], 0, 0, 0);
        acc[i][j] = __builtin_amdgcn_mfma_f32_16x16x32_f16(al[i], bhf[j], acc[i][j], 0, 0, 0);
        acc[i][j] = __builtin_amdgcn_mfma_f32_16x16x32_f16(ah[i], blf[j], acc[i][j], 0, 0, 0);
      }
    __syncthreads();
  }

#pragma unroll
  for (int j = 0; j < 4; ++j) {
    const int col = tileN + wn * 64 + j * 16 + fr;
    const float bias = bx[col] + bh[col];
#pragma unroll
    for (int i = 0; i < 4; ++i) {
      const int row0 = tileM + wm * 64 + i * 16 + ((lane >> 4) << 2);
#pragma unroll
      for (int r = 0; r < 4; ++r)
        C[(long)(row0 + r) * G_ + col] = (XGT)(acc[i][j][r] + bias);
    }
  }
}

// ---------------- flag reset (every launch, stream-ordered) ----------------
__global__ void zero_counters(unsigned int* c) { c[threadIdx.x] = 0; }

// ---------------- persistent LSTM scan ----------------
// 256 WGs x 256 threads, 1 WG/CU (LDS-limited). WG = (bg, hs); wave w = gate w.
// Wh fragments live in LDS (128KB, fragment-linear: conflict-free ds_read_b128),
// loaded ONCE. Barrier: per-WG release flags + wave-parallel polling (no RMW
// contention). h double-buffered in global (hi+lo f16 split for precision).
template <typename XGT>
__global__ __launch_bounds__(256, 1) void lstm_scan(
    const XGT* __restrict__ xg, const _Float16* __restrict__ Whh,
    _Float16* __restrict__ hhi0, _Float16* __restrict__ hhi1,
    _Float16* __restrict__ hlo0, _Float16* __restrict__ hlo1,
    float* __restrict__ out, float* __restrict__ hT, float* __restrict__ cT,
    unsigned int* __restrict__ flags) {
  __shared__ __align__(16) _Float16 WhF[4][32][64][8];  // 128 KB
  __shared__ float gbuf[4][16][16];                     // 4 KB
  const int bg = blockIdx.x >> 6;
  const int hs = blockIdx.x & 63;
  const int tid = threadIdx.x;
  const int w = tid >> 6;
  const int lane = tid & 63;
  const int fr = lane & 15;
  const int fk = (lane >> 4) << 3;

  // ---- Wh -> LDS fragments, once. WhF[w][tile][lane] = Wh[gate w][hs*16+fr][32*tile+fk .. +8]
  {
    const _Float16* wrow = Whh + (long)(w * H_ + hs * 16 + fr) * H_ + fk;
#pragma unroll
    for (int tile = 0; tile < 32; ++tile)
      *(f16x8*)&WhF[w][tile][lane][0] = *(const f16x8*)(wrow + 32 * tile);
  }
  // each wave reads only the fragments it wrote; no cross-wave sync needed

  const int b = tid >> 4, j = tid & 15;
  const int gb = bg * 16 + b;
  const int gj = hs * 16 + j;
  float c = 0.f;

  // xg prefetch for t=0
  float gi = (float)xg[(long)gb * G_ + gj];
  float gf = (float)xg[(long)gb * G_ + gj + H_];
  float gg = (float)xg[(long)gb * G_ + gj + 2 * H_];
  float go = (float)xg[(long)gb * G_ + gj + 3 * H_];

  const long hoff = (long)(bg * 16 + fr) * H_ + fk;

  for (int t = 0; t < S_; ++t) {
    if (t > 0) {
      // read h written at t-1 (buffer (t-1)&1)
      const _Float16* hh = ((t & 1) ? hhi0 : hhi1) + hoff;
      const _Float16* hl = ((t & 1) ? hlo0 : hlo1) + hoff;
      f32x4 acc0 = {}, acc1 = {};
#pragma unroll
      for (int tile = 0; tile < 32; tile += 2) {
        const int kk = 32 * tile;
        const f16x8 wf0 = *(const f16x8*)&WhF[w][tile][lane][0];
        const f16x8 wf1 = *(const f16x8*)&WhF[w][tile + 1][lane][0];
        acc0 = __builtin_amdgcn_mfma_f32_16x16x32_f16(*(const f16x8*)(hh + kk), wf0, acc0, 0, 0, 0);
        acc0 = __builtin_amdgcn_mfma_f32_16x16x32_f16(*(const f16x8*)(hl + kk), wf0, acc0, 0, 0, 0);
        acc1 = __builtin_amdgcn_mfma_f32_16x16x32_f16(*(const f16x8*)(hh + kk + 32), wf1, acc1, 0, 0, 0);
        acc1 = __builtin_amdgcn_mfma_f32_16x16x32_f16(*(const f16x8*)(hl + kk + 32), wf1, acc1, 0, 0, 0);
      }
#pragma unroll
      for (int r = 0; r < 4; ++r)
        gbuf[w][((lane >> 4) << 2) + r][fr] = acc0[r] + acc1[r];
      __syncthreads();
      gi += gbuf[0][b][j];
      gf += gbuf[1][b][j];
      gg += gbuf[2][b][j];
      go += gbuf[3][b][j];
    }

    const float iv = 1.f / (1.f + __expf(-gi));
    const float fv = 1.f / (1.f + __expf(-gf));
    const float gv = tanhf(gg);
    const float ov = 1.f / (1.f + __expf(-go));
    c = fv * c + iv * gv;
    const float hn = ov * tanhf(c);

    // write h for step t+1 into buffer t&1
    _Float16* whi = ((t & 1) ? hhi1 : hhi0);
    _Float16* wlo = ((t & 1) ? hlo1 : hlo0);
    const _Float16 hh16 = (_Float16)hn;
    whi[gb * H_ + gj] = hh16;
    wlo[gb * H_ + gj] = (_Float16)(hn - (float)hh16);
    out[((long)gb * S_ + t) * H_ + gj] = hn;

    if (t + 1 < S_) {
      // prefetch next xg (immutable; safe to issue before the barrier)
      const XGT* xq = xg + ((long)(t + 1) * B_ + gb) * G_ + gj;
      gi = (float)xq[0];
      gf = (float)xq[H_];
      gg = (float)xq[2 * H_];
      go = (float)xq[3 * H_];

      __syncthreads();  // all WG stores issued (vmcnt drained at barrier)
      if (tid == 0)     // arrive: release store to OUR flag (no RMW contention)
        __hip_atomic_store(&flags[blockIdx.x], (unsigned)(t + 1), __ATOMIC_RELEASE,
                           __HIP_MEMORY_SCOPE_AGENT);
      if (w == 0) {     // wait: 64 lanes poll the group's 64 flags in parallel
        unsigned int* fbase = flags + bg * 64;
        const unsigned tgt = (unsigned)(t + 1);
        for (;;) {
          const unsigned v =
              __hip_atomic_load(&fbase[lane], __ATOMIC_RELAXED, __HIP_MEMORY_SCOPE_AGENT);
          if (__all(v >= tgt)) break;
          __builtin_amdgcn_s_sleep(1);
        }
      }
      __syncthreads();
      // per-thread acquire: invalidate caches, order next h reads after the barrier
      (void)__hip_atomic_load(&flags[blockIdx.x], __ATOMIC_ACQUIRE, __HIP_MEMORY_SCOPE_AGENT);
    } else {
      hT[gb * H_ + gj] = hn;
      cT[gb * H_ + gj] = c;
    }
  }
}

// ---------------- launch ----------------
extern "C" void kernel_launch(void* const* d_in, const int* in_sizes, int n_in,
                              void* d_out, int out_size, void* d_ws, size_t ws_size,
                              hipStream_t stream) {
  const float* x = (const float*)d_in[0];
  const float* Wx = (const float*)d_in[1];
  const float* bx = (const float*)d_in[2];
  const float* Wh = (const float*)d_in[3];
  const float* bh = (const float*)d_in[4];

  float* out = (float*)d_out;            // [64][512][1024]
  float* hT = out + (long)B_ * S_ * H_;  // [64][1024]
  float* cT = hT + (long)B_ * H_;        // [64][1024]

  char* ws = (char*)d_ws;
  _Float16* Wxhi = (_Float16*)ws;                     // 8 MB
  _Float16* Wxlo = (_Float16*)(ws + (8l << 20));      // 8 MB
  _Float16* Whh = (_Float16*)(ws + (16l << 20));      // 8 MB
  char* st = ws + (24l << 20);
  _Float16* hhi0 = (_Float16*)(st);                   // 128 KB
  _Float16* hhi1 = (_Float16*)(st + (128l << 10));    // 128 KB
  _Float16* hlo0 = (_Float16*)(st + (256l << 10));    // 128 KB
  _Float16* hlo1 = (_Float16*)(st + (384l << 10));    // 128 KB
  unsigned int* flags = (unsigned int*)(st + (512l << 10));  // 1 KB (256 flags)
  char* xg_raw = ws + (32l << 20);

  cvt_split<<<256, 256, 0, stream>>>(Wx, Wxhi, Wxlo, G_ * I_);
  cvt_f32_f16<<<256, 256, 0, stream>>>(Wh, Whh, G_ * H_);
  zero_counters<<<1, 256, 0, stream>>>(flags);

  const size_t needA = (32ll << 20) + (long long)S_ * B_ * G_ * 4;  // f32 x_gates
  const int nGemmBlk = (S_ * B_ / 128) * (G_ / 128);

  if (ws_size >= needA) {
    float* xg = (float*)xg_raw;
    gemm_xg<float><<<nGemmBlk, 256, 0, stream>>>(x, Wxhi, Wxlo, bx, bh, xg);
    lstm_scan<float><<<256, 256, 0, stream>>>(xg, Whh, hhi0, hhi1, hlo0, hlo1, out, hT, cT, flags);
  } else {
    _Float16* xg = (_Float16*)xg_raw;
    gemm_xg<_Float16><<<nGemmBlk, 256, 0, stream>>>(x, Wxhi, Wxlo, bx, bh, xg);
    lstm_scan<_Float16><<<256, 256, 0, stream>>>(xg, Whh, hhi0, hhi1, hlo0, hlo1, out, hT, cT, flags);
  }
}

// Round 5
// 3114.804 us; speedup vs baseline: 4.5494x; 4.0054x over previous
//
#include <hip/hip_runtime.h>

#define S_ 512
#define B_ 64
#define I_ 1024
#define H_ 1024
#define G_ 4096  // 4*H

typedef _Float16 f16x4 __attribute__((ext_vector_type(4)));
typedef _Float16 f16x8 __attribute__((ext_vector_type(8)));
typedef float f32x4 __attribute__((ext_vector_type(4)));

// ---------------- f32 -> f16 (plain) ----------------
__global__ __launch_bounds__(256) void cvt_f32_f16(const float* __restrict__ src,
                                                   _Float16* __restrict__ dst, int n) {
  const int stride = gridDim.x * blockDim.x * 4;
  for (long i = (long)(blockIdx.x * blockDim.x + threadIdx.x) * 4; i < n; i += stride) {
    const float4 v = *(const float4*)(src + i);
    f16x4 o;
    o.x = (_Float16)v.x;
    o.y = (_Float16)v.y;
    o.z = (_Float16)v.z;
    o.w = (_Float16)v.w;
    *(f16x4*)(dst + i) = o;
  }
}

// ---------------- f32 -> (f16 hi, f16 lo) split ----------------
__global__ __launch_bounds__(256) void cvt_split(const float* __restrict__ src,
                                                 _Float16* __restrict__ hi,
                                                 _Float16* __restrict__ lo, int n) {
  const int stride = gridDim.x * blockDim.x * 4;
  for (long i = (long)(blockIdx.x * blockDim.x + threadIdx.x) * 4; i < n; i += stride) {
    const float4 v = *(const float4*)(src + i);
    f16x4 h, l;
    h.x = (_Float16)v.x; l.x = (_Float16)(v.x - (float)h.x);
    h.y = (_Float16)v.y; l.y = (_Float16)(v.y - (float)h.y);
    h.z = (_Float16)v.z; l.z = (_Float16)(v.z - (float)h.z);
    h.w = (_Float16)v.w; l.w = (_Float16)(v.w - (float)h.w);
    *(f16x4*)(hi + i) = h;
    *(f16x4*)(lo + i) = l;
  }
}

// ---------------- async global->LDS helper (16B per lane) ----------------
__device__ __forceinline__ void gload16(const void* g, void* l) {
  __builtin_amdgcn_global_load_lds(
      (const __attribute__((address_space(1))) unsigned int*)g,
      (__attribute__((address_space(3))) unsigned int*)l, 16, 0, 0);
}

// ---------------- coherent (bypass L1/L2, served by MALL) access helpers ----------------
__device__ __forceinline__ uint4 ld_coh_x4(const unsigned int* p) {
  uint4 v;
  asm volatile("global_load_dwordx4 %0, %1, off sc0 sc1" : "=v"(v) : "v"(p) : "memory");
  return v;
}
__device__ __forceinline__ unsigned ld_coh_wait(const unsigned int* p) {
  unsigned v;
  asm volatile("global_load_dword %0, %1, off sc0 sc1\n\ts_waitcnt vmcnt(0)"
               : "=v"(v) : "v"(p) : "memory");
  return v;
}
__device__ __forceinline__ void st_coh(unsigned int* p, unsigned int v) {
  asm volatile("global_store_dword %0, %1, off sc0 sc1" : : "v"(p), "v"(v) : "memory");
}
__device__ __forceinline__ void wait_vm0() {
  asm volatile("s_waitcnt vmcnt(0)" ::: "memory");
}
__device__ __forceinline__ f16x8 ld_g_f16x8(const _Float16* p) {
  f16x8 v;
  asm volatile("global_load_dwordx4 %0, %1, off" : "=v"(v) : "v"(p) : "memory");
  return v;
}

// ---------------- x_gates GEMM (unchanged, verified R2-R4) ----------------
template <typename XGT>
__global__ __launch_bounds__(256) void gemm_xg(const float* __restrict__ A,
                                               const _Float16* __restrict__ Bhi,
                                               const _Float16* __restrict__ Blo,
                                               const float* __restrict__ bx,
                                               const float* __restrict__ bh,
                                               XGT* __restrict__ C) {
  __shared__ __align__(16) float As[128 * 32];
  __shared__ __align__(16) _Float16 BsH[128 * 32];
  __shared__ __align__(16) _Float16 BsL[128 * 32];
  const int tileN = (blockIdx.x & 31) << 7;
  const int tileM = (blockIdx.x >> 5) << 7;
  const int w = threadIdx.x >> 6;
  const int lane = threadIdx.x & 63;
  const int wm = w & 1, wn = w >> 1;

  const int arow = lane >> 3;
  const int acol = (lane & 7) << 2;
  const float* ap0 = A + (long)(tileM + (4 * w + 0) * 8 + arow) * I_ + acol;
  const float* ap1 = A + (long)(tileM + (4 * w + 1) * 8 + arow) * I_ + acol;
  const float* ap2 = A + (long)(tileM + (4 * w + 2) * 8 + arow) * I_ + acol;
  const float* ap3 = A + (long)(tileM + (4 * w + 3) * 8 + arow) * I_ + acol;
  const int brow = lane >> 2;
  const int bcol = (lane & 3) << 3;
  const _Float16* bh0 = Bhi + (long)(tileN + (2 * w + 0) * 16 + brow) * I_ + bcol;
  const _Float16* bh1 = Bhi + (long)(tileN + (2 * w + 1) * 16 + brow) * I_ + bcol;
  const _Float16* bl0 = Blo + (long)(tileN + (2 * w + 0) * 16 + brow) * I_ + bcol;
  const _Float16* bl1 = Blo + (long)(tileN + (2 * w + 1) * 16 + brow) * I_ + bcol;

  f32x4 acc[4][4] = {};
  const int fr = lane & 15;
  const int fk = (lane >> 4) << 3;

  for (int kk = 0; kk < I_; kk += 32) {
    gload16(ap0 + kk, &As[(4 * w + 0) * 256]);
    gload16(ap1 + kk, &As[(4 * w + 1) * 256]);
    gload16(ap2 + kk, &As[(4 * w + 2) * 256]);
    gload16(ap3 + kk, &As[(4 * w + 3) * 256]);
    gload16(bh0 + kk, &BsH[(2 * w + 0) * 512]);
    gload16(bh1 + kk, &BsH[(2 * w + 1) * 512]);
    gload16(bl0 + kk, &BsL[(2 * w + 0) * 512]);
    gload16(bl1 + kk, &BsL[(2 * w + 1) * 512]);
    __syncthreads();
    f16x8 ah[4], al[4], bhf[4], blf[4];
#pragma unroll
    for (int i = 0; i < 4; ++i) {
      const float* ap = &As[(wm * 64 + i * 16 + fr) * 32 + fk];
      const float4 v0 = *(const float4*)ap;
      const float4 v1 = *(const float4*)(ap + 4);
      float vv[8] = {v0.x, v0.y, v0.z, v0.w, v1.x, v1.y, v1.z, v1.w};
#pragma unroll
      for (int j = 0; j < 8; ++j) {
        const _Float16 hi = (_Float16)vv[j];
        ah[i][j] = hi;
        al[i][j] = (_Float16)(vv[j] - (float)hi);
      }
      bhf[i] = *(const f16x8*)&BsH[(wn * 64 + i * 16 + fr) * 32 + fk];
      blf[i] = *(const f16x8*)&BsL[(wn * 64 + i * 16 + fr) * 32 + fk];
    }
#pragma unroll
    for (int i = 0; i < 4; ++i)
#pragma unroll
      for (int j = 0; j < 4; ++j) {
        acc[i][j] = __builtin_amdgcn_mfma_f32_16x16x32_f16(ah[i], bhf[j], acc[i][j], 0, 0, 0);
        acc[i][j] = __builtin_amdgcn_mfma_f32_16x16x32_f16(al[i], bhf[j], acc[i][j], 0, 0, 0);
        acc[i][j] = __builtin_amdgcn_mfma_f32_16x16x32_f16(ah[i], blf[j], acc[i][j], 0, 0, 0);
      }
    __syncthreads();
  }

#pragma unroll
  for (int j = 0; j < 4; ++j) {
    const int col = tileN + wn * 64 + j * 16 + fr;
    const float bias = bx[col] + bh[col];
#pragma unroll
    for (int i = 0; i < 4; ++i) {
      const int row0 = tileM + wm * 64 + i * 16 + ((lane >> 4) << 2);
#pragma unroll
      for (int r = 0; r < 4; ++r)
        C[(long)(row0 + r) * G_ + col] = (XGT)(acc[i][j][r] + bias);
    }
  }
}

// ---------------- flag reset (every launch, stream-ordered) ----------------
__global__ void zero_counters(unsigned int* c) { c[threadIdx.x] = 0; }

// ---------------- persistent LSTM scan ----------------
// 256 WGs x 256 threads (4 waves), 1 WG/CU. WG=(bg,hs); wave w = gate w.
// Wh pinned in 128 VGPR/lane via inline-asm loads (non-rematerializable).
// h state: packed (f16 hi | f16 lo) u32, exchanged through MALL with sc0/sc1
// coherent accesses -- NO wbl2/inv cache maintenance. Staged once per WG into
// padded LDS (conflict-free ds_read_b128), shared by all 4 waves.
template <typename XGT>
__global__ __launch_bounds__(256, 1) void lstm_scan(
    const XGT* __restrict__ xg, const _Float16* __restrict__ Whh,
    unsigned int* __restrict__ hp0, unsigned int* __restrict__ hp1,
    float* __restrict__ out, float* __restrict__ hT, float* __restrict__ cT,
    unsigned int* __restrict__ flags) {
  // padded rows: 1024 f16 + 8 pad = 2064 B/row -> row stride 516 dwords (%32==4),
  // 16-lane column reads spread across banks (2-way max = free).
  __shared__ __align__(16) char hhS[16 * 2064];
  __shared__ __align__(16) char hlS[16 * 2064];
  __shared__ float gbuf[4][16][16];
  const int bg = blockIdx.x >> 6;
  const int hs = blockIdx.x & 63;
  const int tid = threadIdx.x;
  const int w = tid >> 6;
  const int lane = tid & 63;
  const int fr = lane & 15;
  const int fk = (lane >> 4) << 3;

  // ---- Wh -> VGPRs, once, via asm loads (compiler cannot re-sink these) ----
  f16x8 wreg[32];
  {
    const _Float16* wrow = Whh + (long)(w * H_ + hs * 16 + fr) * H_ + fk;
#pragma unroll
    for (int tile = 0; tile < 32; ++tile) wreg[tile] = ld_g_f16x8(wrow + 32 * tile);
    wait_vm0();
    __builtin_amdgcn_sched_barrier(0);
  }

  const int b = tid >> 4, j = tid & 15;
  const int gb = bg * 16 + b;
  const int gj = hs * 16 + j;
  float c = 0.f;

  const unsigned int* hsrc_base0 = hp0 + bg * 16 * 1024;
  const unsigned int* hsrc_base1 = hp1 + bg * 16 * 1024;
  unsigned int* const myflag = flags + blockIdx.x;
  const unsigned int* const grpflags = flags + bg * 64 + lane;

  // xg prefetch for t=0
  float gi = (float)xg[(long)gb * G_ + gj];
  float gf = (float)xg[(long)gb * G_ + gj + H_];
  float gg = (float)xg[(long)gb * G_ + gj + 2 * H_];
  float go = (float)xg[(long)gb * G_ + gj + 3 * H_];

  const char* hhrow = hhS + fr * 2064 + 2 * fk;
  const char* hlrow = hlS + fr * 2064 + 2 * fk;

  for (int t = 0; t < S_; ++t) {
    if (t > 0) {
      // ---- wait for all 64 WGs of this batch-group to publish h(t-1) ----
      const unsigned tgt = (unsigned)t;
      while (!__all(ld_coh_wait(grpflags) >= tgt)) __builtin_amdgcn_s_sleep(1);

      // ---- stage h(t-1): 64KB packed u32 -> unpack -> LDS (hi, lo) ----
      const unsigned int* hsrc = ((t & 1) ? hsrc_base0 : hsrc_base1);
      uint4 q[16];
#pragma unroll
      for (int i = 0; i < 16; ++i) q[i] = ld_coh_x4(hsrc + (tid << 2) + (i << 10));
      wait_vm0();
      __builtin_amdgcn_sched_barrier(0);
#pragma unroll
      for (int i = 0; i < 16; ++i) {
        const int boff = i * 2064 + (tid << 3);
        uint2 hh, hl;
        hh.x = (q[i].x & 0xffffu) | (q[i].y << 16);
        hh.y = (q[i].z & 0xffffu) | (q[i].w << 16);
        hl.x = (q[i].x >> 16) | (q[i].y & 0xffff0000u);
        hl.y = (q[i].z >> 16) | (q[i].w & 0xffff0000u);
        *(uint2*)(hhS + boff) = hh;
        *(uint2*)(hlS + boff) = hl;
      }
      __syncthreads();

      // ---- gates = (h_hi + h_lo) @ Wh^T from LDS x VGPR-resident Wh ----
      f32x4 acc0 = {}, acc1 = {};
#pragma unroll
      for (int it = 0; it < 16; ++it) {
        const int off = it * 128;
        const f16x8 hh0 = *(const f16x8*)(hhrow + off);
        const f16x8 hl0 = *(const f16x8*)(hlrow + off);
        const f16x8 hh1 = *(const f16x8*)(hhrow + off + 64);
        const f16x8 hl1 = *(const f16x8*)(hlrow + off + 64);
        acc0 = __builtin_amdgcn_mfma_f32_16x16x32_f16(hh0, wreg[2 * it], acc0, 0, 0, 0);
        acc0 = __builtin_amdgcn_mfma_f32_16x16x32_f16(hl0, wreg[2 * it], acc0, 0, 0, 0);
        acc1 = __builtin_amdgcn_mfma_f32_16x16x32_f16(hh1, wreg[2 * it + 1], acc1, 0, 0, 0);
        acc1 = __builtin_amdgcn_mfma_f32_16x16x32_f16(hl1, wreg[2 * it + 1], acc1, 0, 0, 0);
      }
#pragma unroll
      for (int r = 0; r < 4; ++r)
        gbuf[w][((lane >> 4) << 2) + r][fr] = acc0[r] + acc1[r];
      __syncthreads();
      gi += gbuf[0][b][j];
      gf += gbuf[1][b][j];
      gg += gbuf[2][b][j];
      go += gbuf[3][b][j];
    }

    const float iv = 1.f / (1.f + __expf(-gi));
    const float fv = 1.f / (1.f + __expf(-gf));
    const float gv = tanhf(gg);
    const float ov = 1.f / (1.f + __expf(-go));
    c = fv * c + iv * gv;
    const float hn = ov * tanhf(c);

    // ---- publish h(t): packed coherent store (single writer per address) ----
    const _Float16 hi16 = (_Float16)hn;
    const _Float16 lo16 = (_Float16)(hn - (float)hi16);
    const unsigned pk = (unsigned)__builtin_bit_cast(unsigned short, hi16) |
                        ((unsigned)__builtin_bit_cast(unsigned short, lo16) << 16);
    st_coh(((t & 1) ? hp1 : hp0) + gb * 1024 + gj, pk);
    out[((long)gb * S_ + t) * H_ + gj] = hn;

    if (t + 1 < S_) {
      wait_vm0();        // h (and out) stores globally visible (MALL ack)
      __syncthreads();   // all 4 waves of this WG drained
      if (tid == 0) st_coh(myflag, (unsigned)(t + 1));
      // prefetch next xg -- overlaps with the next poll
      const XGT* xq = xg + ((long)(t + 1) * B_ + gb) * G_ + gj;
      gi = (float)xq[0];
      gf = (float)xq[H_];
      gg = (float)xq[2 * H_];
      go = (float)xq[3 * H_];
    } else {
      hT[gb * H_ + gj] = hn;
      cT[gb * H_ + gj] = c;
    }
  }
}

// ---------------- launch ----------------
extern "C" void kernel_launch(void* const* d_in, const int* in_sizes, int n_in,
                              void* d_out, int out_size, void* d_ws, size_t ws_size,
                              hipStream_t stream) {
  const float* x = (const float*)d_in[0];
  const float* Wx = (const float*)d_in[1];
  const float* bx = (const float*)d_in[2];
  const float* Wh = (const float*)d_in[3];
  const float* bh = (const float*)d_in[4];

  float* out = (float*)d_out;            // [64][512][1024]
  float* hT = out + (long)B_ * S_ * H_;  // [64][1024]
  float* cT = hT + (long)B_ * H_;        // [64][1024]

  char* ws = (char*)d_ws;
  _Float16* Wxhi = (_Float16*)ws;                  // 8 MB
  _Float16* Wxlo = (_Float16*)(ws + (8l << 20));   // 8 MB
  _Float16* Whh = (_Float16*)(ws + (16l << 20));   // 8 MB
  char* st = ws + (24l << 20);
  unsigned int* hp0 = (unsigned int*)(st);                    // 256 KB
  unsigned int* hp1 = (unsigned int*)(st + (256l << 10));     // 256 KB
  unsigned int* flags = (unsigned int*)(st + (512l << 10));   // 1 KB
  char* xg_raw = ws + (32l << 20);

  cvt_split<<<256, 256, 0, stream>>>(Wx, Wxhi, Wxlo, G_ * I_);
  cvt_f32_f16<<<256, 256, 0, stream>>>(Wh, Whh, G_ * H_);
  zero_counters<<<1, 256, 0, stream>>>(flags);

  const size_t needA = (32ll << 20) + (long long)S_ * B_ * G_ * 4;  // f32 x_gates
  const int nGemmBlk = (S_ * B_ / 128) * (G_ / 128);

  if (ws_size >= needA) {
    float* xg = (float*)xg_raw;
    gemm_xg<float><<<nGemmBlk, 256, 0, stream>>>(x, Wxhi, Wxlo, bx, bh, xg);
    lstm_scan<float><<<256, 256, 0, stream>>>(xg, Whh, hp0, hp1, out, hT, cT, flags);
  } else {
    _Float16* xg = (_Float16*)xg_raw;
    gemm_xg<_Float16><<<nGemmBlk, 256, 0, stream>>>(x, Wxhi, Wxlo, bx, bh, xg);
    lstm_scan<_Float16><<<256, 256, 0, stream>>>(xg, Whh, hp0, hp1, out, hT, cT, flags);
  }
}